// Round 1
// baseline (857.130 us; speedup 1.0000x reference)
//
#include <hip/hip_runtime.h>
#include <hip/hip_bf16.h>

namespace {

constexpr int L_  = 16;
constexpr int P_  = 1024;
constexpr int DV_ = 64;
constexpr int DP_ = 16;
constexpr int B_  = 128;
constexpr int PC_ = 16;   // p's per workgroup in heavy kernels
constexpr int BC_ = 16;   // b's per workgroup in heavy kernels

__device__ __forceinline__ float dot16(const float4 w[4], const float4 x[4]) {
  float u = 0.f;
#pragma unroll
  for (int i = 0; i < 4; ++i) {
    u = fmaf(w[i].x, x[i].x, u);
    u = fmaf(w[i].y, x[i].y, u);
    u = fmaf(w[i].z, x[i].z, u);
    u = fmaf(w[i].w, x[i].w, u);
  }
  return u;
}

// s[b,l,v] += sum_p c[b,l,p] * u[b,l,p,v]   (c = 1/16 when UNIFORM)
// thread (l = tid>>6, v = tid&63); grid (P/PC, B/BC); W kept in regs per p,
// reused across BC b's; feature table in LDS (broadcast reads).
template<bool UNIFORM>
__global__ __launch_bounds__(1024, 1) void k_wsum(
    const float* __restrict__ Wq, const float* __restrict__ feat,
    const int* __restrict__ sel, const int* __restrict__ nsrc_p,
    const float* __restrict__ cbuf, float* __restrict__ sbuf)
{
  __shared__ float feat_lds[B_ * DP_];
  const int tid = threadIdx.x;
  for (int i = tid; i < B_ * DP_; i += 1024) feat_lds[i] = feat[i];
  __syncthreads();
  const int n_src = *nsrc_p;
  const int l = tid >> 6;
  const int v = tid & 63;
  const int p0 = blockIdx.x * PC_;
  const int b0 = blockIdx.y * BC_;

  float acc[BC_];
#pragma unroll
  for (int i = 0; i < BC_; ++i) acc[i] = 0.f;

  for (int pp = 0; pp < PC_; ++pp) {
    const int p = p0 + pp;
    const float4* wp = reinterpret_cast<const float4*>(
        Wq + (((size_t)l * P_ + p) * DV_ + v) * DP_);
    float4 wr[4];
#pragma unroll
    for (int i = 0; i < 4; ++i) wr[i] = wp[i];

#pragma unroll
    for (int bb = 0; bb < BC_; ++bb) {
      const int b = b0 + bb;
      const int j = sel[b * P_ + p] + (b >= n_src ? n_src : 0);
      const float4* xp = reinterpret_cast<const float4*>(&feat_lds[j * DP_]);
      float4 xr[4];
#pragma unroll
      for (int i = 0; i < 4; ++i) xr[i] = xp[i];
      const float u = dot16(wr, xr);
      const float cw = UNIFORM ? 0.0625f
                               : cbuf[((size_t)b * L_ + l) * P_ + p];
      acc[bb] = fmaf(cw, u, acc[bb]);
    }
  }
#pragma unroll
  for (int bb = 0; bb < BC_; ++bb)
    atomicAdd(&sbuf[((b0 + bb) * L_ + l) * DV_ + v], acc[bb]);
}

// d[b,l,p] = sum_v vv[b,l,v]*u[b,l,p,v]  (+ bprev[b,l,p] when ADDB)
template<bool ADDB>
__global__ __launch_bounds__(1024, 1) void k_dotv(
    const float* __restrict__ Wq, const float* __restrict__ feat,
    const int* __restrict__ sel, const int* __restrict__ nsrc_p,
    const float* __restrict__ vv, const float* __restrict__ bprev,
    float* __restrict__ dout)
{
  __shared__ float feat_lds[B_ * DP_];
  const int tid = threadIdx.x;
  for (int i = tid; i < B_ * DP_; i += 1024) feat_lds[i] = feat[i];
  __syncthreads();
  const int n_src = *nsrc_p;
  const int l = tid >> 6;
  const int v = tid & 63;
  const int p0 = blockIdx.x * PC_;
  const int b0 = blockIdx.y * BC_;

  float vvr[BC_];
#pragma unroll
  for (int bb = 0; bb < BC_; ++bb)
    vvr[bb] = vv[((b0 + bb) * L_ + l) * DV_ + v];

  for (int pp = 0; pp < PC_; ++pp) {
    const int p = p0 + pp;
    const float4* wp = reinterpret_cast<const float4*>(
        Wq + (((size_t)l * P_ + p) * DV_ + v) * DP_);
    float4 wr[4];
#pragma unroll
    for (int i = 0; i < 4; ++i) wr[i] = wp[i];

#pragma unroll
    for (int bb = 0; bb < BC_; ++bb) {
      const int b = b0 + bb;
      const int j = sel[b * P_ + p] + (b >= n_src ? n_src : 0);
      const float4* xp = reinterpret_cast<const float4*>(&feat_lds[j * DP_]);
      float4 xr[4];
#pragma unroll
      for (int i = 0; i < 4; ++i) xr[i] = xp[i];
      float t = vvr[bb] * dot16(wr, xr);
#pragma unroll
      for (int m = 32; m >= 1; m >>= 1) t += __shfl_xor(t, m, 64);
      if (v == 0) {
        const size_t o = ((size_t)b * L_ + l) * P_ + p;
        float d = t;
        if (ADDB) d += bprev[o];
        dout[o] = d;
      }
    }
  }
}

// softmax over l (axis of size 16, stride P) for each (b,p)
__global__ __launch_bounds__(256) void k_softmax_l(
    const float* __restrict__ lin, float* __restrict__ lout)
{
  const int idx = blockIdx.x * 256 + threadIdx.x;
  const int b = idx >> 10;
  const int p = idx & (P_ - 1);
  const float* base = lin + (size_t)b * L_ * P_ + p;
  float x[L_];
  float m = -1e30f;
#pragma unroll
  for (int l = 0; l < L_; ++l) { x[l] = base[l * P_]; m = fmaxf(m, x[l]); }
  float den = 0.f;
#pragma unroll
  for (int l = 0; l < L_; ++l) { x[l] = __expf(x[l] - m); den += x[l]; }
  const float r = 1.f / den;
  float* ob = lout + (size_t)b * L_ * P_ + p;
#pragma unroll
  for (int l = 0; l < L_; ++l) ob[l * P_] = x[l] * r;
}

// squash each 64-elem row: out = s*sqrt(sn)/(1+sn), sn = sum(s^2)
__global__ __launch_bounds__(256) void k_squash(
    const float* __restrict__ sbuf, float* __restrict__ vout)
{
  const int row = blockIdx.x * 4 + (threadIdx.x >> 6);
  const int v = threadIdx.x & 63;
  const float s = sbuf[row * DV_ + v];
  float t = s * s;
#pragma unroll
  for (int m = 32; m >= 1; m >>= 1) t += __shfl_xor(t, m, 64);
  vout[row * DV_ + v] = s * sqrtf(t) / (1.f + t);
}

// final squash + norms:  norms[l,b] = sn/(1+sn)
__global__ __launch_bounds__(256) void k_final(
    const float* __restrict__ sbuf, float* __restrict__ caps,
    float* __restrict__ norms)
{
  const int row = blockIdx.x * 4 + (threadIdx.x >> 6);
  const int v = threadIdx.x & 63;
  const float s = sbuf[row * DV_ + v];
  float t = s * s;
#pragma unroll
  for (int m = 32; m >= 1; m >>= 1) t += __shfl_xor(t, m, 64);
  caps[row * DV_ + v] = s * sqrtf(t) / (1.f + t);
  if (v == 0) {
    const int b = row >> 4;
    const int l = row & (L_ - 1);
    norms[l * B_ + b] = t / (1.f + t);
  }
}

} // namespace

extern "C" void kernel_launch(void* const* d_in, const int* in_sizes, int n_in,
                              void* d_out, int out_size, void* d_ws, size_t ws_size,
                              hipStream_t stream)
{
  (void)in_sizes; (void)n_in; (void)out_size; (void)ws_size;
  const float* feat   = (const float*)d_in[0];
  const int*   sel    = (const int*)d_in[1];
  const float* Wq     = (const float*)d_in[2];
  const int*   nsrc_p = (const int*)d_in[3];

  float* caps  = (float*)d_out;                       // [B,L,DV]
  float* norms = caps + (size_t)B_ * L_ * DV_;        // [L,B]

  constexpr size_t SLV = (size_t)B_ * L_ * DV_;       // 131072
  constexpr size_t BLP = (size_t)B_ * L_ * P_;        // 2M
  float* s1   = (float*)d_ws;
  float* s2   = s1 + SLV;
  float* s3   = s2 + SLV;
  float* v1   = s3 + SLV;
  float* v2   = v1 + SLV;
  float* b1   = v2 + SLV;      // [B,L,P] logits after iter 1
  float* bufA = b1 + BLP;      // [B,L,P] scratch (c2 / b2 / c3)

  hipMemsetAsync(s1, 0, 3 * SLV * sizeof(float), stream);

  const dim3 gH(P_ / PC_, B_ / BC_), bH(1024);
  const dim3 gS(B_ * P_ / 256), bS(256);
  const dim3 gQ(B_ * L_ / 4), bQ(256);

  // iter 1: c uniform -> s1 -> v1 ; b1 = <v1,u>
  k_wsum<true ><<<gH, bH, 0, stream>>>(Wq, feat, sel, nsrc_p, nullptr, s1);
  k_squash     <<<gQ, bQ, 0, stream>>>(s1, v1);
  k_dotv<false><<<gH, bH, 0, stream>>>(Wq, feat, sel, nsrc_p, v1, nullptr, b1);
  // iter 2: c2 = softmax(b1) -> s2 -> v2 ; b2 = b1 + <v2,u>
  k_softmax_l  <<<gS, bS, 0, stream>>>(b1, bufA);
  k_wsum<false><<<gH, bH, 0, stream>>>(Wq, feat, sel, nsrc_p, bufA, s2);
  k_squash     <<<gQ, bQ, 0, stream>>>(s2, v2);
  k_dotv<true ><<<gH, bH, 0, stream>>>(Wq, feat, sel, nsrc_p, v2, b1, bufA);
  // final: c3 = softmax(b2) -> s3 -> caps/norms
  k_softmax_l  <<<gS, bS, 0, stream>>>(bufA, bufA);
  k_wsum<false><<<gH, bH, 0, stream>>>(Wq, feat, sel, nsrc_p, bufA, s3);
  k_final      <<<gQ, bQ, 0, stream>>>(s3, caps, norms);
}

// Round 2
// 266.382 us; speedup vs baseline: 3.2177x; 3.2177x over previous
//
#include <hip/hip_runtime.h>
#include <hip/hip_bf16.h>

namespace {

constexpr int L_  = 16;
constexpr int P_  = 1024;
constexpr int DV_ = 64;
constexpr int DP_ = 16;
constexpr int B_  = 128;

constexpr size_t PB   = (size_t)P_ * B_;          // 131072 (one l-plane of [l][p][b])
constexpr size_t SLV  = (size_t)B_ * L_ * DV_;    // 131072
constexpr size_t LPBT = (size_t)L_ * PB;          // 2M (logits buffer elems)

constexpr int KCH = 32;           // wsum k-chunks; each covers P_/KCH p's
constexpr int PPC = P_ / KCH;     // 32 p per wsum block
constexpr int MCH = 64;           // dotv m-chunks; each 16 p (8 m-tiles of 32 rows)

typedef __attribute__((ext_vector_type(8)))  short bf16x8;
typedef __attribute__((ext_vector_type(16))) float f32x16;

// pack two floats into bf16 pair (compiler emits v_cvt_pk_bf16_f32)
__device__ __forceinline__ void pack2(bf16x8& d, int i, float lo, float hi) {
  __hip_bfloat162 t = __float22bfloat162_rn(float2{lo, hi});
  short2 s = *reinterpret_cast<short2*>(&t);
  d[2 * i] = s.x;
  d[2 * i + 1] = s.y;
}

// j-table: jbuf[p][b] = sel[b][p] + (b >= n_src ? n_src : 0)
__global__ __launch_bounds__(256) void k_prep(
    const int* __restrict__ sel, const int* __restrict__ nsrc_p,
    int* __restrict__ jbuf)
{
  const int i = blockIdx.x * 256 + threadIdx.x;   // b*1024 + p
  const int b = i >> 10, p = i & (P_ - 1);
  const int ns = *nsrc_p;
  jbuf[p * B_ + b] = sel[i] + (b >= ns ? ns : 0);
}

// s[b,l,v] = sum_{p,q} W[l,p,v,q] * c[b,l,p] * feat[j(b,p),q]
// MFMA 32x32x16: A[v,k] from W (contiguous q), B[k,b] built from feat+c.
// grid (KCH, L); 4 waves, wave w owns b-tile w*32; kstep = one p.
template<bool UNIFORM, bool USE_PART>
__global__ __launch_bounds__(256) void k_wsum(
    const float* __restrict__ W, const float* __restrict__ feat,
    const int* __restrict__ jbuf, const float* __restrict__ cbuf,
    float* __restrict__ out)   // spart if USE_PART else s (atomic)
{
  const int l    = blockIdx.y;
  const int kc   = blockIdx.x;
  const int wave = threadIdx.x >> 6;
  const int lane = threadIdx.x & 63;
  const int col  = lane & 31;
  const int h    = lane >> 5;
  const int bcol = wave * 32 + col;

  f32x16 acc0, acc1;
#pragma unroll
  for (int r = 0; r < 16; ++r) { acc0[r] = 0.f; acc1[r] = 0.f; }

  const int p_begin = kc * PPC;
#pragma unroll 2
  for (int ps = 0; ps < PPC; ++ps) {
    const int p = p_begin + ps;

    // B fragment: y[k=(p,q), b] = cw * feat[j, q], q = h*8 + j
    const int jj = jbuf[p * B_ + bcol];
    const float cw = UNIFORM ? 0.0625f
                             : cbuf[(size_t)l * PB + (size_t)p * B_ + bcol];
    const float4* fx = reinterpret_cast<const float4*>(feat + jj * DP_ + h * 8);
    const float4 f0 = fx[0], f1 = fx[1];
    bf16x8 bfrag;
    pack2(bfrag, 0, cw * f0.x, cw * f0.y);
    pack2(bfrag, 1, cw * f0.z, cw * f0.w);
    pack2(bfrag, 2, cw * f1.x, cw * f1.y);
    pack2(bfrag, 3, cw * f1.z, cw * f1.w);

    // A fragments: row v = m0 + col, cols q = h*8 + j (contiguous in W)
    const float* wa0 = W + (((size_t)l * P_ + p) * DV_ + col) * DP_ + h * 8;
    const float* wa1 = wa0 + (size_t)32 * DP_;
    const float4 w00 = *(const float4*)wa0, w01 = *(const float4*)(wa0 + 4);
    const float4 w10 = *(const float4*)wa1, w11 = *(const float4*)(wa1 + 4);
    bf16x8 a0, a1;
    pack2(a0, 0, w00.x, w00.y); pack2(a0, 1, w00.z, w00.w);
    pack2(a0, 2, w01.x, w01.y); pack2(a0, 3, w01.z, w01.w);
    pack2(a1, 0, w10.x, w10.y); pack2(a1, 1, w10.z, w10.w);
    pack2(a1, 2, w11.x, w11.y); pack2(a1, 3, w11.z, w11.w);

    acc0 = __builtin_amdgcn_mfma_f32_32x32x16_bf16(a0, bfrag, acc0, 0, 0, 0);
    acc1 = __builtin_amdgcn_mfma_f32_32x32x16_bf16(a1, bfrag, acc1, 0, 0, 0);
  }

  if (USE_PART) {
    float* op = out + ((size_t)l * KCH + kc) * ((size_t)DV_ * B_);
#pragma unroll
    for (int r = 0; r < 16; ++r) {
      const int v0 = (r & 3) + 8 * (r >> 2) + 4 * h;
      op[(size_t)v0 * B_ + bcol]        = acc0[r];
      op[(size_t)(v0 + 32) * B_ + bcol] = acc1[r];
    }
  } else {
#pragma unroll
    for (int r = 0; r < 16; ++r) {
      const int v0 = (r & 3) + 8 * (r >> 2) + 4 * h;
      atomicAdd(&out[((size_t)bcol * L_ + l) * DV_ + v0],      acc0[r]);
      atomicAdd(&out[((size_t)bcol * L_ + l) * DV_ + v0 + 32], acc1[r]);
    }
  }
}

// s[(b,l,v)] = sum over KCH chunks of spart[l][chunk][v*128+b]
__global__ __launch_bounds__(256) void k_reduce_s(
    const float* __restrict__ spart, float* __restrict__ s)
{
  const int idx = blockIdx.x * 256 + threadIdx.x;  // l*8192 + v*128 + b
  const int l  = idx >> 13;
  const int vb = idx & 8191;
  const float* sp = spart + (size_t)l * KCH * 8192 + vb;
  float t = 0.f;
#pragma unroll
  for (int c = 0; c < KCH; ++c) t += sp[(size_t)c * 8192];
  const int v = vb >> 7, b = vb & 127;
  s[((size_t)b * L_ + l) * DV_ + v] = t;
}

// d[l][p][b] = sum_v vv[b,l,v] * u[b,l,p,v]  (+ bprev when ADDB)
// MFMA: C[(p,q),b] = sum_v W[l,p,v,q]*vv[b,l,v]; epilogue folds sum_q feat*C.
template<bool ADDB>
__global__ __launch_bounds__(256) void k_dotv(
    const float* __restrict__ W, const float* __restrict__ feat,
    const int* __restrict__ jbuf, const float* __restrict__ vv,
    const float* __restrict__ bprev, float* __restrict__ dout)
{
  const int l    = blockIdx.y;
  const int mc   = blockIdx.x;
  const int wave = threadIdx.x >> 6;
  const int lane = threadIdx.x & 63;
  const int col  = lane & 31;
  const int h    = lane >> 5;
  const int bcol = wave * 32 + col;

  // hoist B-frags from vv (K=64 -> 4 ksteps), k = ks*16 + h*8 + j
  bf16x8 bf[4];
#pragma unroll
  for (int ks = 0; ks < 4; ++ks) {
    const float* vp = vv + ((size_t)bcol * L_ + l) * DV_ + ks * 16 + h * 8;
    const float4 v0 = *(const float4*)vp, v1 = *(const float4*)(vp + 4);
    pack2(bf[ks], 0, v0.x, v0.y); pack2(bf[ks], 1, v0.z, v0.w);
    pack2(bf[ks], 2, v1.x, v1.y); pack2(bf[ks], 3, v1.z, v1.w);
  }

  const int p_base = mc * 16;
  const int prow_off = (col >> 4);          // 0 or 1: which p within tile
  const int q = col & 15;

#pragma unroll 2
  for (int mt = 0; mt < 8; ++mt) {
    const int p0 = p_base + mt * 2;
    const int prow = p0 + prow_off;

    f32x16 acc;
#pragma unroll
    for (int r = 0; r < 16; ++r) acc[r] = 0.f;

#pragma unroll
    for (int ks = 0; ks < 4; ++ks) {
      const int vb = ks * 16 + h * 8;
      const float* wp = W + (((size_t)l * P_ + prow) * DV_ + vb) * DP_ + q;
      bf16x8 af;
#pragma unroll
      for (int j = 0; j < 4; ++j)
        pack2(af, j, wp[(size_t)(2 * j) * DP_], wp[(size_t)(2 * j + 1) * DP_]);
      acc = __builtin_amdgcn_mfma_f32_32x32x16_bf16(af, bf[ks], acc, 0, 0, 0);
    }

    // epilogue: d[b,p] = sum_q feat[j(b,p),q] * C[(p,q),b]
    const int j0 = jbuf[p0 * B_ + bcol];
    const int j1 = jbuf[(p0 + 1) * B_ + bcol];
    float d0 = 0.f, d1 = 0.f;
#pragma unroll
    for (int r = 0; r < 8; ++r) {
      const int q_r = (r & 3) + 8 * (r >> 2) + 4 * h;
      d0 = fmaf(acc[r],     feat[j0 * DP_ + q_r], d0);
      d1 = fmaf(acc[r + 8], feat[j1 * DP_ + q_r], d1);
    }
    d0 += __shfl_xor(d0, 32);
    d1 += __shfl_xor(d1, 32);
    if (h == 0) {
      const size_t o0 = (size_t)l * PB + (size_t)p0 * B_ + bcol;
      const size_t o1 = o0 + B_;
      float w0 = d0, w1 = d1;
      if (ADDB) { w0 += bprev[o0]; w1 += bprev[o1]; }
      dout[o0] = w0;
      dout[o1] = w1;
    }
  }
}

// softmax over l for each (p,b); buffers are [l][p][b]
__global__ __launch_bounds__(256) void k_softmax_l(
    const float* __restrict__ lin, float* __restrict__ lout)
{
  const int idx = blockIdx.x * 256 + threadIdx.x;  // p*128 + b
  const float* ip = lin + idx;
  float x[L_];
  float m = -1e30f;
#pragma unroll
  for (int l = 0; l < L_; ++l) { x[l] = ip[(size_t)l * PB]; m = fmaxf(m, x[l]); }
  float den = 0.f;
#pragma unroll
  for (int l = 0; l < L_; ++l) { x[l] = __expf(x[l] - m); den += x[l]; }
  const float r = 1.f / den;
  float* op = lout + idx;
#pragma unroll
  for (int l = 0; l < L_; ++l) op[(size_t)l * PB] = x[l] * r;
}

// squash each 64-elem row of s ([b][l][v] layout)
__global__ __launch_bounds__(256) void k_squash(
    const float* __restrict__ sbuf, float* __restrict__ vout)
{
  const int row = blockIdx.x * 4 + (threadIdx.x >> 6);
  const int v = threadIdx.x & 63;
  const float s = sbuf[(size_t)row * DV_ + v];
  float t = s * s;
#pragma unroll
  for (int m = 32; m >= 1; m >>= 1) t += __shfl_xor(t, m, 64);
  vout[(size_t)row * DV_ + v] = s * sqrtf(t) / (1.f + t);
}

__global__ __launch_bounds__(256) void k_final(
    const float* __restrict__ sbuf, float* __restrict__ caps,
    float* __restrict__ norms)
{
  const int row = blockIdx.x * 4 + (threadIdx.x >> 6);
  const int v = threadIdx.x & 63;
  const float s = sbuf[(size_t)row * DV_ + v];
  float t = s * s;
#pragma unroll
  for (int m = 32; m >= 1; m >>= 1) t += __shfl_xor(t, m, 64);
  caps[(size_t)row * DV_ + v] = s * sqrtf(t) / (1.f + t);
  if (v == 0) {
    const int b = row >> 4;
    const int l = row & (L_ - 1);
    norms[(size_t)l * B_ + b] = t / (1.f + t);
  }
}

} // namespace

extern "C" void kernel_launch(void* const* d_in, const int* in_sizes, int n_in,
                              void* d_out, int out_size, void* d_ws, size_t ws_size,
                              hipStream_t stream)
{
  (void)in_sizes; (void)n_in; (void)out_size;
  const float* feat   = (const float*)d_in[0];
  const int*   sel    = (const int*)d_in[1];
  const float* W      = (const float*)d_in[2];
  const int*   nsrc_p = (const int*)d_in[3];

  float* caps  = (float*)d_out;                 // [B,L,DV]
  float* norms = caps + SLV;                    // [L,B]

  float* s1    = (float*)d_ws;
  float* s2    = s1 + SLV;
  float* s3    = s2 + SLV;
  float* v1    = s3 + SLV;
  float* v2    = v1 + SLV;
  float* bb1   = v2 + SLV;                      // [l][p][b] b-logits iter1
  float* bufc  = bb1 + LPBT;                    // [l][p][b] c / b2 scratch
  int*   jbuf  = (int*)(bufc + LPBT);           // [p][b]
  float* spart = (float*)(jbuf + PB);           // [l][KCH][v*128+b]

  const size_t need_elems = 5 * SLV + 2 * LPBT + PB + (size_t)L_ * KCH * 8192;
  const bool use_part = ws_size >= need_elems * sizeof(float);

  const dim3 blk(256);
  const dim3 gW(KCH, L_);
  const dim3 gD(MCH, L_);
  const dim3 gF(512);

  k_prep<<<gF, blk, 0, stream>>>(sel, nsrc_p, jbuf);
  if (!use_part)
    hipMemsetAsync(s1, 0, 3 * SLV * sizeof(float), stream);

  // ---- iter 1: uniform c -> s1 -> v1 ; b1 = <v1,u> ----
  if (use_part) {
    k_wsum<true, true><<<gW, blk, 0, stream>>>(W, feat, jbuf, nullptr, spart);
    k_reduce_s<<<gF, blk, 0, stream>>>(spart, s1);
  } else {
    k_wsum<true, false><<<gW, blk, 0, stream>>>(W, feat, jbuf, nullptr, s1);
  }
  k_squash<<<gF, blk, 0, stream>>>(s1, v1);
  k_dotv<false><<<gD, blk, 0, stream>>>(W, feat, jbuf, v1, nullptr, bb1);

  // ---- iter 2: c2 = softmax(b1) -> s2 -> v2 ; b2 = b1 + <v2,u> ----
  k_softmax_l<<<gF, blk, 0, stream>>>(bb1, bufc);
  if (use_part) {
    k_wsum<false, true><<<gW, blk, 0, stream>>>(W, feat, jbuf, bufc, spart);
    k_reduce_s<<<gF, blk, 0, stream>>>(spart, s2);
  } else {
    k_wsum<false, false><<<gW, blk, 0, stream>>>(W, feat, jbuf, bufc, s2);
  }
  k_squash<<<gF, blk, 0, stream>>>(s2, v2);
  k_dotv<true><<<gD, blk, 0, stream>>>(W, feat, jbuf, v2, bb1, bufc);

  // ---- final: c3 = softmax(b2) -> s3 -> caps/norms ----
  k_softmax_l<<<gF, blk, 0, stream>>>(bufc, bufc);
  if (use_part) {
    k_wsum<false, true><<<gW, blk, 0, stream>>>(W, feat, jbuf, bufc, spart);
    k_reduce_s<<<gF, blk, 0, stream>>>(spart, s3);
  } else {
    k_wsum<false, false><<<gW, blk, 0, stream>>>(W, feat, jbuf, bufc, s3);
  }
  k_final<<<gF, blk, 0, stream>>>(s3, caps, norms);
}